// Round 5
// baseline (1114.956 us; speedup 1.0000x reference)
//
#include <hip/hip_runtime.h>
#include <hip/hip_fp16.h>

#define HID 64

struct alignas(8)  H4 { __half2 a, b; };
struct alignas(16) H8 { __half2 h[4]; };

typedef _Float16 f16x8 __attribute__((ext_vector_type(8)));
typedef float    f32x4 __attribute__((ext_vector_type(4)));

// ===========================================================================
// CSR build: histogram + scan + permutation (+ fp16 edge-feature reorder)
// ===========================================================================
__global__ __launch_bounds__(256) void deg_count(const int* __restrict__ dst,
                                                 int* __restrict__ deg, int E) {
    int e = blockIdx.x * 256 + threadIdx.x;
    if (e < E) atomicAdd(&deg[dst[e]], 1);
}

__global__ __launch_bounds__(256) void scan1(const int* __restrict__ deg,
                                             int* __restrict__ rowptr,
                                             int* __restrict__ bsums, int N) {
    __shared__ int s[256];
    const int t = threadIdx.x;
    const int base = blockIdx.x * 2048 + t * 8;
    int v[8], tot = 0;
    #pragma unroll
    for (int i = 0; i < 8; i++) {
        int x = (base + i < N) ? deg[base + i] : 0;
        v[i] = tot; tot += x;
    }
    s[t] = tot; __syncthreads();
    for (int off = 1; off < 256; off <<= 1) {
        int a = (t >= off) ? s[t - off] : 0;
        __syncthreads(); s[t] += a; __syncthreads();
    }
    const int texcl = s[t] - tot;
    #pragma unroll
    for (int i = 0; i < 8; i++)
        if (base + i < N) rowptr[base + i] = texcl + v[i];
    if (t == 255) bsums[blockIdx.x] = s[255];
}

__global__ void scan2(int* bsums, int NB) {
    if (blockIdx.x == 0 && threadIdx.x == 0) {
        int run = 0;
        for (int i = 0; i < NB; i++) { int x = bsums[i]; bsums[i] = run; run += x; }
    }
}

__global__ __launch_bounds__(256) void scan3(int* __restrict__ rowptr,
                                             const int* __restrict__ bsums,
                                             int N, int E) {
    int idx = blockIdx.x * 256 + threadIdx.x;
    if (idx < N) rowptr[idx] += bsums[idx >> 11];
    if (idx == 0) rowptr[N] = E;
}

// pk = (src << 6) | (dst & 63)  -- 6-bit local dst for 64-node tiles
__global__ __launch_bounds__(256) void permute_k(
    const int* __restrict__ src, const int* __restrict__ dst,
    const int* __restrict__ rowptr, int* __restrict__ cursor,
    const float* __restrict__ Xe, __half* __restrict__ Xes,
    unsigned* __restrict__ pks, int E)
{
    int e = blockIdx.x * 256 + threadIdx.x;
    if (e >= E) return;
    int d = dst[e];
    int pos = rowptr[d] + atomicAdd(&cursor[d], 1);
    pks[pos] = ((unsigned)src[e] << 6) | (unsigned)(d & 63);
    const float4* xi = (const float4*)&Xe[(size_t)e * 16];
    float4 x0 = xi[0], x1 = xi[1], x2 = xi[2], x3 = xi[3];
    H8 h0, h1;
    h0.h[0] = __float22half2_rn(make_float2(x0.x, x0.y));
    h0.h[1] = __float22half2_rn(make_float2(x0.z, x0.w));
    h0.h[2] = __float22half2_rn(make_float2(x1.x, x1.y));
    h0.h[3] = __float22half2_rn(make_float2(x1.z, x1.w));
    h1.h[0] = __float22half2_rn(make_float2(x2.x, x2.y));
    h1.h[1] = __float22half2_rn(make_float2(x2.z, x2.w));
    h1.h[2] = __float22half2_rn(make_float2(x3.x, x3.y));
    h1.h[3] = __float22half2_rn(make_float2(x3.z, x3.w));
    H8* xo = (H8*)&Xes[(size_t)pos * 16];
    xo[0] = h0; xo[1] = h1;
}

// ===========================================================================
// pm_dual: PMs[n] = fp16(h@Wm_top + bm)  (COLUMN-SWIZZLED: half index
//          n*64 + (c&15)*4 + (c>>4) so a lane's 8B gather = cols {c,c+16,c+32,c+48})
//          Th[n]  = fp16(h@Wu_top + bu)  (linear)
// ===========================================================================
template<int K1>
__global__ __launch_bounds__(256) void pm_dual(
    const float* __restrict__ Hn,
    const float* __restrict__ Wm, const float* __restrict__ bm,
    const float* __restrict__ Wu, const float* __restrict__ bu,
    __half* __restrict__ PMs, __half* __restrict__ Th, int N)
{
    constexpr int KP = K1 + 4;
    constexpr int P4 = K1 / 4;
    __shared__ float Ws[K1 * 128];
    __shared__ float Xs[32 * KP];

    const int tid = threadIdx.x;
    for (int i = tid; i < K1 * 32; i += 256) {
        const int row = i >> 5, c4 = i & 31;
        float4 v = (c4 < 16) ? *(const float4*)&Wm[row * 64 + c4 * 4]
                             : *(const float4*)&Wu[row * 64 + (c4 - 16) * 4];
        *(float4*)&Ws[row * 128 + c4 * 4] = v;
    }
    const int nbase = blockIdx.x * 32;
    for (int i = tid; i < 32 * P4; i += 256) {
        const int nl = i / P4, part = i % P4;
        const int n = nbase + nl;
        if (n < N)
            *(float4*)&Xs[nl * KP + part * 4] =
                *(const float4*)&Hn[(size_t)n * K1 + part * 4];
    }
    __syncthreads();

    const int c0 = (tid & 31) * 4;
    const int n0 = (tid >> 5) * 4;
    const float4 bv = (c0 < 64) ? *(const float4*)&bm[c0]
                                : *(const float4*)&bu[c0 - 64];

    float4 acc[4];
    #pragma unroll
    for (int i = 0; i < 4; i++) acc[i] = bv;

    #pragma unroll 4
    for (int k = 0; k < K1; k += 4) {
        const float4 w0 = *(const float4*)&Ws[(k + 0) * 128 + c0];
        const float4 w1 = *(const float4*)&Ws[(k + 1) * 128 + c0];
        const float4 w2 = *(const float4*)&Ws[(k + 2) * 128 + c0];
        const float4 w3 = *(const float4*)&Ws[(k + 3) * 128 + c0];
        #pragma unroll
        for (int ni = 0; ni < 4; ni++) {
            const float4 xv = *(const float4*)&Xs[(n0 + ni) * KP + k];
            acc[ni].x += xv.x * w0.x + xv.y * w1.x + xv.z * w2.x + xv.w * w3.x;
            acc[ni].y += xv.x * w0.y + xv.y * w1.y + xv.z * w2.y + xv.w * w3.y;
            acc[ni].z += xv.x * w0.z + xv.y * w1.z + xv.z * w2.z + xv.w * w3.z;
            acc[ni].w += xv.x * w0.w + xv.y * w1.w + xv.z * w2.w + xv.w * w3.w;
        }
    }

    #pragma unroll
    for (int ni = 0; ni < 4; ni++) {
        const int n = nbase + n0 + ni;
        if (n < N) {
            if (c0 < 64) {
                // swizzled scatter: col c -> n*64 + (c&15)*4 + (c>>4)
                const int cb = c0 & 15, hb = c0 >> 4;
                PMs[(size_t)n * 64 + (cb + 0) * 4 + hb] = __float2half_rn(acc[ni].x);
                PMs[(size_t)n * 64 + (cb + 1) * 4 + hb] = __float2half_rn(acc[ni].y);
                PMs[(size_t)n * 64 + (cb + 2) * 4 + hb] = __float2half_rn(acc[ni].z);
                PMs[(size_t)n * 64 + (cb + 3) * 4 + hb] = __float2half_rn(acc[ni].w);
            } else {
                H4 o;
                o.a = __float22half2_rn(make_float2(acc[ni].x, acc[ni].y));
                o.b = __float22half2_rn(make_float2(acc[ni].z, acc[ni].w));
                *(H4*)&Th[(size_t)n * 64 + c0 - 64] = o;
            }
        }
    }
}

// ===========================================================================
// edge_fused v4 (MFMA, TILE=64, 3-ahead gathers): per 16-edge chunk, one
// mfma_f32_16x16x32_f16 per 16-col block; PM gather is the MFMA C-init.
// Changes vs v3: TILE 32->64 (16 chunks/wave, prologue share 3/16), PM
// gathers issued 3 chunks ahead (ring 4), prefetch clamps are BLOCK-LOCAL
// (tail reads hit warm L2 lines instead of far end of array), upper-K lanes
// (q>=2) skip the Xes load entirely (their A-fragment is zero).
// ===========================================================================
__global__ __launch_bounds__(256) void edge_fused(
    const __half*   __restrict__ PMs,   // [N,64] col-swizzled (see pm_dual)
    const __half*   __restrict__ Th,    // [N,64] linear
    const __half*   __restrict__ Xes,   // [E,16] dst-sorted
    const unsigned* __restrict__ pks,   // [E] (src<<6)|(dst&63)
    const int*      __restrict__ rowptr,
    const float*    __restrict__ Mwb,   // [16,64]
    const float*    __restrict__ Uwb,   // [64,64]
    float*          __restrict__ Yout,  // [N,64]
    int N, int Etot)
{
    constexpr int TILE = 64;
    constexpr int AGP  = HID + 4;
    __shared__ float aggs[TILE * AGP];  // 17408 B

    const int tid  = threadIdx.x;
    const int wv   = tid >> 6;
    const int lane = tid & 63;
    const int q    = lane >> 4;         // k-octet select (A/B), row-quad (C)
    const int li   = lane & 15;         // edge row (A) / out col (C) in-block
    const int sl0  = q * 4;             // first C row (edge) this lane holds

    // B fragments: bfr[b][i] = Mwb[8q+i][16b+li], zero for k>=16 (q>=2)
    f16x8 bfr[4];
    #pragma unroll
    for (int b = 0; b < 4; b++) {
        #pragma unroll
        for (int i = 0; i < 8; i++) {
            float w = (q < 2) ? Mwb[(8 * q + i) * 64 + 16 * b + li] : 0.f;
            bfr[b][i] = (_Float16)w;
        }
    }

    for (int i = tid; i < TILE * AGP; i += 256) aggs[i] = 0.f;

    const int nbase  = blockIdx.x * TILE;
    const int nend   = (nbase + TILE < N) ? nbase + TILE : N;
    const int estart = rowptr[nbase];
    const int eend   = rowptr[nend];
    __syncthreads();

    const int pc0   = estart + wv * 16;
    const int qXl   = q * 64 + li;      // pkv gather-lane offset (4 chunks/load)
    const int ecapK = eend - 1;         // per-lane pk clamp (block-local)
    const int ecapX = (eend - 16 > 0) ? eend - 16 : 0;  // chunk-base clamp

    unsigned pkv[2];      // each: 64 pks = 4 chunks (lane l: chunk l>>4, edge l&15)
    uint4    xq[4];       // A-frag bytes per chunk (ring 4)
    H4       ph[4][4];    // PM gathers (C-init), ring 4, 4 edges/lane
    unsigned ldp[4];      // 4x packed local-dst (8-bit fields), ring 4

#define LOAD_PKV(B, CB) do {                                                  \
    int e_ = (CB) + qXl; e_ = e_ < ecapK ? e_ : ecapK;                        \
    pkv[B] = pks[e_];                                                         \
} while (0)

#define LOAD_XQ(S, CB) do {                                                   \
    int b_ = (CB); b_ = b_ <= ecapX ? b_ : ecapX;                             \
    uint4 t_ = make_uint4(0u, 0u, 0u, 0u);                                    \
    if (q < 2)                                                                \
        t_ = *(const uint4*)((const char*)Xes + (size_t)(b_ + li) * 32        \
                             + (q << 4));                                     \
    xq[S] = t_;                                                               \
} while (0)

#define GATH(S, PB, D4) do {                                                  \
    unsigned l_ = 0;                                                          \
    _Pragma("unroll")                                                         \
    for (int j = 0; j < 4; j++) {                                             \
        unsigned pk_ = (unsigned)__shfl((int)pkv[PB], (D4) * 16 + sl0 + j);   \
        ph[S][j] = *(const H4*)((const char*)PMs +                            \
                                ((size_t)(pk_ >> 6) << 7) + li * 8);          \
        l_ |= (pk_ & 63u) << (8 * j);                                         \
    }                                                                         \
    ldp[S] = l_;                                                              \
} while (0)

#define COMPUTE(S, PCC) do {                                                  \
    f16x8 a; __builtin_memcpy(&a, &xq[S], 16);                                \
    f32x4 acc0, acc1, acc2, acc3;                                             \
    _Pragma("unroll")                                                         \
    for (int j = 0; j < 4; j++) {                                             \
        const float2 g0 = __half22float2(ph[S][j].a);                         \
        const float2 g1 = __half22float2(ph[S][j].b);                         \
        acc0[j] = g0.x; acc1[j] = g0.y; acc2[j] = g1.x; acc3[j] = g1.y;       \
    }                                                                         \
    acc0 = __builtin_amdgcn_mfma_f32_16x16x32_f16(a, bfr[0], acc0, 0, 0, 0);  \
    acc1 = __builtin_amdgcn_mfma_f32_16x16x32_f16(a, bfr[1], acc1, 0, 0, 0);  \
    acc2 = __builtin_amdgcn_mfma_f32_16x16x32_f16(a, bfr[2], acc2, 0, 0, 0);  \
    acc3 = __builtin_amdgcn_mfma_f32_16x16x32_f16(a, bfr[3], acc3, 0, 0, 0);  \
    int ld_prev = -1;                                                         \
    f32x4 racc = {0.f, 0.f, 0.f, 0.f};                                        \
    _Pragma("unroll")                                                         \
    for (int j = 0; j < 4; j++) {                                             \
        f32x4 v;                                                              \
        v[0] = fmaxf(acc0[j], 0.f); v[1] = fmaxf(acc1[j], 0.f);               \
        v[2] = fmaxf(acc2[j], 0.f); v[3] = fmaxf(acc3[j], 0.f);               \
        const int ld = ((PCC) + sl0 + j < eend)                               \
                     ? (int)((ldp[S] >> (8 * j)) & 63u) : -1;                 \
        if (ld == ld_prev) {                                                  \
            racc[0] += v[0]; racc[1] += v[1];                                 \
            racc[2] += v[2]; racc[3] += v[3];                                 \
        } else {                                                              \
            if (ld_prev >= 0) {                                               \
                float* a_ = &aggs[ld_prev * AGP + li];                        \
                atomicAdd(a_ +  0, racc[0]); atomicAdd(a_ + 16, racc[1]);     \
                atomicAdd(a_ + 32, racc[2]); atomicAdd(a_ + 48, racc[3]);     \
            }                                                                 \
            racc = v; ld_prev = ld;                                           \
        }                                                                     \
    }                                                                         \
    if (ld_prev >= 0) {                                                       \
        float* a_ = &aggs[ld_prev * AGP + li];                                \
        atomicAdd(a_ +  0, racc[0]); atomicAdd(a_ + 16, racc[1]);             \
        atomicAdd(a_ + 32, racc[2]); atomicAdd(a_ + 48, racc[3]);             \
    }                                                                         \
} while (0)

    if (pc0 < eend) {
        // prologue: pkv chunks 0-7; xq chunks 0-3; gathers chunks 0-2
        LOAD_PKV(0, pc0);
        LOAD_PKV(1, pc0 + 256);
        LOAD_XQ(0, pc0);       LOAD_XQ(1, pc0 + 64);
        LOAD_XQ(2, pc0 + 128); LOAD_XQ(3, pc0 + 192);
        GATH(0, 0, 0);
        GATH(1, 0, 1);
        GATH(2, 0, 2);

        // steady state (chunk k per iter): gather k+3 -> stage (k+3)&3 from
        // pkv[((k+3)>>2)&1]; compute k (stage k&3); xq k+4 -> stage k&3.
        // pkv reloads: at k%8==2 buf0 <- chunks k+6..k+9 (base pc+384);
        //              at k%8==6 buf1 <- same offset.
        int pc = pc0;
        while (true) {
            { GATH(3, 0, 3); COMPUTE(0, pc); LOAD_XQ(0, pc + 256); }
            pc += 64; if (pc >= eend) break;
            { GATH(0, 1, 0); COMPUTE(1, pc); LOAD_XQ(1, pc + 256); }
            pc += 64; if (pc >= eend) break;
            { GATH(1, 1, 1); COMPUTE(2, pc); LOAD_XQ(2, pc + 256);
              LOAD_PKV(0, pc + 384); }
            pc += 64; if (pc >= eend) break;
            { GATH(2, 1, 2); COMPUTE(3, pc); LOAD_XQ(3, pc + 256); }
            pc += 64; if (pc >= eend) break;
            { GATH(3, 1, 3); COMPUTE(0, pc); LOAD_XQ(0, pc + 256); }
            pc += 64; if (pc >= eend) break;
            { GATH(0, 0, 0); COMPUTE(1, pc); LOAD_XQ(1, pc + 256); }
            pc += 64; if (pc >= eend) break;
            { GATH(1, 0, 1); COMPUTE(2, pc); LOAD_XQ(2, pc + 256);
              LOAD_PKV(1, pc + 384); }
            pc += 64; if (pc >= eend) break;
            { GATH(2, 0, 2); COMPUTE(3, pc); LOAD_XQ(3, pc + 256); }
            pc += 64; if (pc >= eend) break;
        }
    }

#undef LOAD_PKV
#undef LOAD_XQ
#undef GATH
#undef COMPUTE

    __syncthreads();

    // ---- fused node update: y = relu(T + aggs @ Uw_bot), Uwb via L1 ----
    {
        const int c0t = (tid & 15) * 4;
        const int r0  = tid >> 4;           // 0..15; rows r0 + 16j, j=0..3
        float4 acc[4];
        #pragma unroll
        for (int j = 0; j < 4; j++) {
            const int n = nbase + r0 + 16 * j;
            if (n < N) {
                H4 th = *(const H4*)&Th[(size_t)n * 64 + c0t];
                float2 lo = __half22float2(th.a), hi = __half22float2(th.b);
                acc[j] = make_float4(lo.x, lo.y, hi.x, hi.y);
            } else {
                acc[j] = make_float4(0.f, 0.f, 0.f, 0.f);
            }
        }
        #pragma unroll 4
        for (int k = 0; k < 64; k += 4) {
            const float4 w0 = *(const float4*)&Uwb[(k + 0) * 64 + c0t];
            const float4 w1 = *(const float4*)&Uwb[(k + 1) * 64 + c0t];
            const float4 w2 = *(const float4*)&Uwb[(k + 2) * 64 + c0t];
            const float4 w3 = *(const float4*)&Uwb[(k + 3) * 64 + c0t];
            #pragma unroll
            for (int j = 0; j < 4; j++) {
                const float4 x = *(const float4*)&aggs[(r0 + 16 * j) * AGP + k];
                acc[j].x += x.x * w0.x + x.y * w1.x + x.z * w2.x + x.w * w3.x;
                acc[j].y += x.x * w0.y + x.y * w1.y + x.z * w2.y + x.w * w3.y;
                acc[j].z += x.x * w0.z + x.y * w1.z + x.z * w2.z + x.w * w3.z;
                acc[j].w += x.x * w0.w + x.y * w1.w + x.z * w2.w + x.w * w3.w;
            }
        }
        #pragma unroll
        for (int j = 0; j < 4; j++) {
            const int n = nbase + r0 + 16 * j;
            if (n < N) {
                float4 o;
                o.x = fmaxf(acc[j].x, 0.f); o.y = fmaxf(acc[j].y, 0.f);
                o.z = fmaxf(acc[j].z, 0.f); o.w = fmaxf(acc[j].w, 0.f);
                *(float4*)&Yout[(size_t)n * HID + c0t] = o;
            }
        }
    }
}

// ===========================================================================
// pool_head: out[g] = (sum_{n in graph g} y[n]) . Ww + Wb  (sorted batch_idx)
// ===========================================================================
__global__ __launch_bounds__(256) void pool_head(
    const float* __restrict__ Y, const int* __restrict__ bidx,
    const float* __restrict__ Ww, const float* __restrict__ Wb,
    float* __restrict__ out, int N)
{
    const int g = blockIdx.x;
    int a = 0, b = N;
    while (a < b) { int m = (a + b) >> 1; if (bidx[m] < g) a = m + 1; else b = m; }
    const int lo = a;
    b = N;
    while (a < b) { int m = (a + b) >> 1; if (bidx[m] < g + 1) a = m + 1; else b = m; }
    const int hi = a;

    const int tid = threadIdx.x;
    const int c4 = tid & 15, nl = tid >> 4;
    float4 s = make_float4(0.f, 0.f, 0.f, 0.f);
    for (int n = lo + nl; n < hi; n += 16) {
        const float4 v = *(const float4*)&Y[(size_t)n * HID + c4 * 4];
        s.x += v.x; s.y += v.y; s.z += v.z; s.w += v.w;
    }
    __shared__ float red[16 * 68];
    *(float4*)&red[nl * 68 + c4 * 4] = s;
    __syncthreads();
    if (tid < 64) {
        float t = 0.f;
        #pragma unroll
        for (int r = 0; r < 16; r++) t += red[r * 68 + tid];
        t *= Ww[tid];
        #pragma unroll
        for (int off = 32; off; off >>= 1) t += __shfl_down(t, off);
        if (tid == 0) out[g] = t + Wb[0];
    }
}

extern "C" void kernel_launch(void* const* d_in, const int* in_sizes, int n_in,
                              void* d_out, int out_size, void* d_ws, size_t ws_size,
                              hipStream_t stream) {
    const float* H    = (const float*)d_in[0];
    const float* Xe   = (const float*)d_in[1];
    const int*   ids  = (const int*)d_in[2];
    const int*   bidx = (const int*)d_in[3];
    const float* Mw0  = (const float*)d_in[4];
    const float* Mb0  = (const float*)d_in[5];
    const float* Uw0  = (const float*)d_in[6];
    const float* Ub0  = (const float*)d_in[7];
    const float* MwH  = (const float*)d_in[8];   // [3, 80, 64]
    const float* MbH  = (const float*)d_in[9];
    const float* UwH  = (const float*)d_in[10];  // [3, 128, 64]
    const float* UbH  = (const float*)d_in[11];
    const float* Ww   = (const float*)d_in[12];
    const float* Wb   = (const float*)d_in[13];
    float* out = (float*)d_out;

    const int N = in_sizes[0] / 32;
    const int E = in_sizes[1] / 16;
    const int* src = ids;
    const int* dst = ids + E;

    // ---- workspace (identical layout/footprint to the 964 µs baseline) ----
    float*  hbuf = (float*)d_ws;                       // N*64 f32
    __half* PMs  = (__half*)(hbuf + (size_t)N * HID);  // N*64 h (swizzled)
    __half* Th   = PMs + (size_t)N * HID;              // N*64 h
    __half* Xes  = Th  + (size_t)N * HID;              // E*16 h
    unsigned* pks = (unsigned*)(Xes + (size_t)E * 16); // E u32
    int* rowptr  = (int*)(pks + E);                    // N+1
    int* deg     = rowptr + (N + 1);                   // N
    int* bsums   = deg + N;                            // <=4096

    const int NB = (N + 2047) / 2048;
    const int eblocks = (E + 255) / 256;
    const int ntile32 = (N + 31) / 32;
    const int ntile64 = (N + 63) / 64;

    // ---- CSR build + fp16 edge reorder ----
    hipMemsetAsync(deg, 0, (size_t)N * sizeof(int), stream);
    deg_count<<<eblocks, 256, 0, stream>>>(dst, deg, E);
    scan1<<<NB, 256, 0, stream>>>(deg, rowptr, bsums, N);
    scan2<<<1, 64, 0, stream>>>(bsums, NB);
    scan3<<<(N + 255) / 256, 256, 0, stream>>>(rowptr, bsums, N, E);
    hipMemsetAsync(deg, 0, (size_t)N * sizeof(int), stream);
    permute_k<<<eblocks, 256, 0, stream>>>(src, dst, rowptr, deg,
                                           Xe, Xes, pks, E);

    // ---- layer 0 (K1=32) ----
    pm_dual<32><<<ntile32, 256, 0, stream>>>(H, Mw0, Mb0, Uw0, Ub0, PMs, Th, N);
    edge_fused<<<ntile64, 256, 0, stream>>>(PMs, Th, Xes, pks, rowptr,
                                            Mw0 + 32 * HID, Uw0 + 32 * HID, hbuf, N, E);

    // ---- hidden layers (K1=64) ----
    for (int l = 0; l < 3; l++) {
        const float* Mw = MwH + (size_t)l * 80 * HID;
        const float* Uw = UwH + (size_t)l * 128 * HID;
        pm_dual<64><<<ntile32, 256, 0, stream>>>(hbuf, Mw, MbH + (size_t)l * HID,
                                                 Uw, UbH + (size_t)l * HID, PMs, Th, N);
        edge_fused<<<ntile64, 256, 0, stream>>>(PMs, Th, Xes, pks, rowptr,
                                                Mw + 64 * HID, Uw + 64 * HID, hbuf, N, E);
    }

    // ---- pooling + head ----
    pool_head<<<256, 256, 0, stream>>>(hbuf, bidx, Ww, Wb, out, N);
}

// Round 7
// 914.439 us; speedup vs baseline: 1.2193x; 1.2193x over previous
//
#include <hip/hip_runtime.h>
#include <hip/hip_fp16.h>

#define HID 64

struct alignas(8)  H4 { __half2 a, b; };
struct alignas(16) H8 { __half2 h[4]; };

typedef _Float16 h2n __attribute__((ext_vector_type(2)));

__device__ inline float dot2f(__half2 a, __half2 b, float c) {
#if __has_builtin(__builtin_amdgcn_fdot2)
    h2n an, bn;
    __builtin_memcpy(&an, &a, 4);
    __builtin_memcpy(&bn, &b, 4);
    return __builtin_amdgcn_fdot2(an, bn, c, false);
#else
    float2 af = __half22float2(a), bf = __half22float2(b);
    return c + af.x * bf.x + af.y * bf.y;
#endif
}

// ===========================================================================
// CSR build: histogram + scan + permutation (+ fp16 edge-feature reorder)
// ===========================================================================
__global__ __launch_bounds__(256) void deg_count(const int* __restrict__ dst,
                                                 int* __restrict__ deg, int E) {
    int e = blockIdx.x * 256 + threadIdx.x;
    if (e < E) atomicAdd(&deg[dst[e]], 1);
}

__global__ __launch_bounds__(256) void scan1(const int* __restrict__ deg,
                                             int* __restrict__ rowptr,
                                             int* __restrict__ bsums, int N) {
    __shared__ int s[256];
    const int t = threadIdx.x;
    const int base = blockIdx.x * 2048 + t * 8;
    int v[8], tot = 0;
    #pragma unroll
    for (int i = 0; i < 8; i++) {
        int x = (base + i < N) ? deg[base + i] : 0;
        v[i] = tot; tot += x;
    }
    s[t] = tot; __syncthreads();
    for (int off = 1; off < 256; off <<= 1) {
        int a = (t >= off) ? s[t - off] : 0;
        __syncthreads(); s[t] += a; __syncthreads();
    }
    const int texcl = s[t] - tot;
    #pragma unroll
    for (int i = 0; i < 8; i++)
        if (base + i < N) rowptr[base + i] = texcl + v[i];
    if (t == 255) bsums[blockIdx.x] = s[255];
}

__global__ void scan2(int* bsums, int NB) {
    if (blockIdx.x == 0 && threadIdx.x == 0) {
        int run = 0;
        for (int i = 0; i < NB; i++) { int x = bsums[i]; bsums[i] = run; run += x; }
    }
}

__global__ __launch_bounds__(256) void scan3(int* __restrict__ rowptr,
                                             const int* __restrict__ bsums,
                                             int N, int E) {
    int idx = blockIdx.x * 256 + threadIdx.x;
    if (idx < N) rowptr[idx] += bsums[idx >> 11];
    if (idx == 0) rowptr[N] = E;
}

__global__ __launch_bounds__(256) void permute_k(
    const int* __restrict__ src, const int* __restrict__ dst,
    const int* __restrict__ rowptr, int* __restrict__ cursor,
    const float* __restrict__ Xe, __half* __restrict__ Xes,
    unsigned* __restrict__ pks, int E)
{
    int e = blockIdx.x * 256 + threadIdx.x;
    if (e >= E) return;
    int d = dst[e];
    int pos = rowptr[d] + atomicAdd(&cursor[d], 1);
    pks[pos] = ((unsigned)src[e] << 5) | (unsigned)(d & 31);
    const float4* xi = (const float4*)&Xe[(size_t)e * 16];
    float4 x0 = xi[0], x1 = xi[1], x2 = xi[2], x3 = xi[3];
    H8 h0, h1;
    h0.h[0] = __float22half2_rn(make_float2(x0.x, x0.y));
    h0.h[1] = __float22half2_rn(make_float2(x0.z, x0.w));
    h0.h[2] = __float22half2_rn(make_float2(x1.x, x1.y));
    h0.h[3] = __float22half2_rn(make_float2(x1.z, x1.w));
    h1.h[0] = __float22half2_rn(make_float2(x2.x, x2.y));
    h1.h[1] = __float22half2_rn(make_float2(x2.z, x2.w));
    h1.h[2] = __float22half2_rn(make_float2(x3.x, x3.y));
    h1.h[3] = __float22half2_rn(make_float2(x3.z, x3.w));
    H8* xo = (H8*)&Xes[(size_t)pos * 16];
    xo[0] = h0; xo[1] = h1;
}

// ===========================================================================
// pm_dual: PMh[n] = fp16(h@Wm_top + bm), Th[n] = fp16(h@Wu_top + bu)
// (only used for layer 0 now; hidden-layer PM/Th are fused into edge_fused)
// ===========================================================================
template<int K1>
__global__ __launch_bounds__(256) void pm_dual(
    const float* __restrict__ Hn,
    const float* __restrict__ Wm, const float* __restrict__ bm,
    const float* __restrict__ Wu, const float* __restrict__ bu,
    __half* __restrict__ PMh, __half* __restrict__ Th, int N)
{
    constexpr int KP = K1 + 4;
    constexpr int P4 = K1 / 4;
    __shared__ float Ws[K1 * 128];
    __shared__ float Xs[32 * KP];

    const int tid = threadIdx.x;
    for (int i = tid; i < K1 * 32; i += 256) {
        const int row = i >> 5, c4 = i & 31;
        float4 v = (c4 < 16) ? *(const float4*)&Wm[row * 64 + c4 * 4]
                             : *(const float4*)&Wu[row * 64 + (c4 - 16) * 4];
        *(float4*)&Ws[row * 128 + c4 * 4] = v;
    }
    const int nbase = blockIdx.x * 32;
    for (int i = tid; i < 32 * P4; i += 256) {
        const int nl = i / P4, part = i % P4;
        const int n = nbase + nl;
        if (n < N)
            *(float4*)&Xs[nl * KP + part * 4] =
                *(const float4*)&Hn[(size_t)n * K1 + part * 4];
    }
    __syncthreads();

    const int c0 = (tid & 31) * 4;
    const int n0 = (tid >> 5) * 4;
    const float4 bv = (c0 < 64) ? *(const float4*)&bm[c0]
                                : *(const float4*)&bu[c0 - 64];

    float4 acc[4];
    #pragma unroll
    for (int i = 0; i < 4; i++) acc[i] = bv;

    #pragma unroll 4
    for (int k = 0; k < K1; k += 4) {
        const float4 w0 = *(const float4*)&Ws[(k + 0) * 128 + c0];
        const float4 w1 = *(const float4*)&Ws[(k + 1) * 128 + c0];
        const float4 w2 = *(const float4*)&Ws[(k + 2) * 128 + c0];
        const float4 w3 = *(const float4*)&Ws[(k + 3) * 128 + c0];
        #pragma unroll
        for (int ni = 0; ni < 4; ni++) {
            const float4 xv = *(const float4*)&Xs[(n0 + ni) * KP + k];
            acc[ni].x += xv.x * w0.x + xv.y * w1.x + xv.z * w2.x + xv.w * w3.x;
            acc[ni].y += xv.x * w0.y + xv.y * w1.y + xv.z * w2.y + xv.w * w3.y;
            acc[ni].z += xv.x * w0.z + xv.y * w1.z + xv.z * w2.z + xv.w * w3.z;
            acc[ni].w += xv.x * w0.w + xv.y * w1.w + xv.z * w2.w + xv.w * w3.w;
        }
    }

    #pragma unroll
    for (int ni = 0; ni < 4; ni++) {
        const int n = nbase + n0 + ni;
        if (n < N) {
            H4 o;
            o.a = __float22half2_rn(make_float2(acc[ni].x, acc[ni].y));
            o.b = __float22half2_rn(make_float2(acc[ni].z, acc[ni].w));
            if (c0 < 64) *(H4*)&PMh[(size_t)n * 64 + c0]      = o;
            else         *(H4*)&Th [(size_t)n * 64 + c0 - 64] = o;
        }
    }
}

// ===========================================================================
// edge_fused (v0 main loop, PROVEN 155us) + FUSE epilogue:
//  aggs = sum_e relu(PM[src] + Xe@Mw_bot); y = relu(T + aggs@Uw_bot)
//  if FUSE: additionally compute next layer's PM/Th for this block's 32
//  nodes in-place (y staged in aggs LDS, weights straight from L1) --
//  replaces the separate pm_dual dispatch + hbuf round-trip per layer.
//  [R7: byte-identical resubmit of R6 -- audit found no fault; R3->R4
//   established that identical resubmits of "container failed" rounds pass]
// ===========================================================================
template<bool FUSE>
__global__ __launch_bounds__(256) void edge_fused(
    const __half*   __restrict__ PMh,   // [N, 64]
    const __half*   __restrict__ Th,    // [N, 64]
    const __half*   __restrict__ Xes,   // [E, 16] dst-sorted
    const unsigned* __restrict__ pks,   // [E] (src<<5)|ld
    const int*      __restrict__ rowptr,
    const float*    __restrict__ Mwb,   // [16, 64] message bottom
    const float*    __restrict__ Uwb,   // [64, 64] update bottom
    const float*    __restrict__ MwN,   // [64, 64] next-layer M top (FUSE)
    const float*    __restrict__ MbN,   //          next-layer M bias
    const float*    __restrict__ UwN,   // [64, 64] next-layer U top (FUSE)
    const float*    __restrict__ UbN,   //          next-layer U bias
    __half*         __restrict__ PMo,   // [N, 64] out (FUSE)
    __half*         __restrict__ Tho,   // [N, 64] out (FUSE)
    float*          __restrict__ Yout,  // [N, 64] out (!FUSE, final layer)
    int N)
{
    constexpr int AGP = HID + 4;
    __shared__ float aggs[32 * AGP];    // 8.7 KB (only LDS)

    const int tid  = threadIdx.x;
    const int wv   = tid >> 6;
    const int lane = tid & 63;
    const int c0   = (lane & 15) * 4;
    const int g    = lane >> 4;

    // dot2 weight pairs: wh[p][j] = (Mwb[2p][c0+j], Mwb[2p+1][c0+j])
    __half2 wh[8][4];
    #pragma unroll
    for (int p = 0; p < 8; p++)
        #pragma unroll
        for (int j = 0; j < 4; j++)
            wh[p][j] = __float22half2_rn(make_float2(Mwb[(2 * p) * 64 + c0 + j],
                                                     Mwb[(2 * p + 1) * 64 + c0 + j]));

    for (int i = tid; i < 32 * AGP; i += 256) aggs[i] = 0.f;

    const int nbase  = blockIdx.x * 32;
    const int nend   = (nbase + 32 < N) ? nbase + 32 : N;
    const int estart = rowptr[nbase];
    const int eend   = rowptr[nend];
    __syncthreads();

    int pc = estart + wv * 16;
    unsigned pk_c[4], pk_n[4], pk_n2[4];
    H4 ph_c[4], ph_n[4];
    H8 xh_c[4][2], xh_n[4][2];

    if (pc < eend) {
        // prologue: pk for chunk0 + chunk1, gathers for chunk0
        #pragma unroll
        for (int s = 0; s < 4; s++) {
            const int pe = pc + g * 4 + s;
            pk_c[s] = pks[pe < eend ? pe : eend - 1];
        }
        if (pc + 64 < eend) {
            #pragma unroll
            for (int s = 0; s < 4; s++) {
                const int pe = pc + 64 + g * 4 + s;
                pk_n[s] = pks[pe < eend ? pe : eend - 1];
            }
        }
        #pragma unroll
        for (int s = 0; s < 4; s++) {
            const int pe  = pc + g * 4 + s;
            const int pcl = pe < eend ? pe : eend - 1;
            ph_c[s] = *(const H4*)&PMh[(size_t)(pk_c[s] >> 5) * 64 + c0];
            const H8* xr = (const H8*)&Xes[(size_t)pcl * 16];
            xh_c[s][0] = xr[0]; xh_c[s][1] = xr[1];
        }
    }

    for (; pc < eend; pc += 64) {
        const int pn  = pc + 64;
        const int pn2 = pc + 128;

        // issue gathers for chunk i+1 (pk_n already resident)
        if (pn < eend) {
            #pragma unroll
            for (int s = 0; s < 4; s++) {
                const int pe  = pn + g * 4 + s;
                const int pcl = pe < eend ? pe : eend - 1;
                ph_n[s] = *(const H4*)&PMh[(size_t)(pk_n[s] >> 5) * 64 + c0];
                const H8* xr = (const H8*)&Xes[(size_t)pcl * 16];
                xh_n[s][0] = xr[0]; xh_n[s][1] = xr[1];
            }
        }
        // issue pk for chunk i+2
        if (pn2 < eend) {
            #pragma unroll
            for (int s = 0; s < 4; s++) {
                const int pe = pn2 + g * 4 + s;
                pk_n2[s] = pks[pe < eend ? pe : eend - 1];
            }
        }

        // compute chunk i
        int ld_prev = -1;
        float4 racc = make_float4(0.f, 0.f, 0.f, 0.f);
        #pragma unroll
        for (int s = 0; s < 4; s++) {
            const bool valid = (pc + g * 4 + s) < eend;
            const float2 pl = __half22float2(ph_c[s].a);
            const float2 pu = __half22float2(ph_c[s].b);
            float a0 = pl.x, a1 = pl.y, a2 = pu.x, a3 = pu.y;
            #pragma unroll
            for (int p = 0; p < 8; p++) {
                const __half2 xv = xh_c[s][p >> 2].h[p & 3];
                a0 = dot2f(xv, wh[p][0], a0);
                a1 = dot2f(xv, wh[p][1], a1);
                a2 = dot2f(xv, wh[p][2], a2);
                a3 = dot2f(xv, wh[p][3], a3);
            }
            float4 v;
            v.x = fmaxf(a0, 0.f); v.y = fmaxf(a1, 0.f);
            v.z = fmaxf(a2, 0.f); v.w = fmaxf(a3, 0.f);
            const int ld = valid ? (int)(pk_c[s] & 31u) : -1;
            if (ld == ld_prev) {
                racc.x += v.x; racc.y += v.y; racc.z += v.z; racc.w += v.w;
            } else {
                if (ld_prev >= 0) {
                    float* a = &aggs[ld_prev * AGP + c0];
                    atomicAdd(a + 0, racc.x); atomicAdd(a + 1, racc.y);
                    atomicAdd(a + 2, racc.z); atomicAdd(a + 3, racc.w);
                }
                racc = v; ld_prev = ld;
            }
        }
        if (ld_prev >= 0) {
            float* a = &aggs[ld_prev * AGP + c0];
            atomicAdd(a + 0, racc.x); atomicAdd(a + 1, racc.y);
            atomicAdd(a + 2, racc.z); atomicAdd(a + 3, racc.w);
        }

        // rotate pipeline
        #pragma unroll
        for (int s = 0; s < 4; s++) {
            pk_c[s] = pk_n[s]; pk_n[s] = pk_n2[s];
            ph_c[s] = ph_n[s];
            xh_c[s][0] = xh_n[s][0]; xh_c[s][1] = xh_n[s][1];
        }
    }

    __syncthreads();

    // ---- fused node update: y = relu(T + aggs @ Uw_bot), Uwb via L1 ----
    const int c0t = (tid & 15) * 4;
    const int r0  = tid >> 4;
    const int r1  = r0 + 16;
    const int n0g = nbase + r0, n1g = nbase + r1;
    float4 acc0 = make_float4(0.f, 0.f, 0.f, 0.f);
    float4 acc1 = make_float4(0.f, 0.f, 0.f, 0.f);
    if (n0g < N) {
        H4 th = *(const H4*)&Th[(size_t)n0g * 64 + c0t];
        float2 lo = __half22float2(th.a), hi = __half22float2(th.b);
        acc0 = make_float4(lo.x, lo.y, hi.x, hi.y);
    }
    if (n1g < N) {
        H4 th = *(const H4*)&Th[(size_t)n1g * 64 + c0t];
        float2 lo = __half22float2(th.a), hi = __half22float2(th.b);
        acc1 = make_float4(lo.x, lo.y, hi.x, hi.y);
    }
    #pragma unroll 4
    for (int k = 0; k < 64; k += 4) {
        const float4 w0 = *(const float4*)&Uwb[(k + 0) * 64 + c0t];
        const float4 w1 = *(const float4*)&Uwb[(k + 1) * 64 + c0t];
        const float4 w2 = *(const float4*)&Uwb[(k + 2) * 64 + c0t];
        const float4 w3 = *(const float4*)&Uwb[(k + 3) * 64 + c0t];
        const float4 x0 = *(const float4*)&aggs[r0 * AGP + k];
        const float4 x1 = *(const float4*)&aggs[r1 * AGP + k];
        acc0.x += x0.x * w0.x + x0.y * w1.x + x0.z * w2.x + x0.w * w3.x;
        acc0.y += x0.x * w0.y + x0.y * w1.y + x0.z * w2.y + x0.w * w3.y;
        acc0.z += x0.x * w0.z + x0.y * w1.z + x0.z * w2.z + x0.w * w3.z;
        acc0.w += x0.x * w0.w + x0.y * w1.w + x0.z * w2.w + x0.w * w3.w;
        acc1.x += x1.x * w0.x + x1.y * w1.x + x1.z * w2.x + x1.w * w3.x;
        acc1.y += x1.x * w0.y + x1.y * w1.y + x1.z * w2.y + x1.w * w3.y;
        acc1.z += x1.x * w0.z + x1.y * w1.z + x1.z * w2.z + x1.w * w3.z;
        acc1.w += x1.x * w0.w + x1.y * w1.w + x1.z * w2.w + x1.w * w3.w;
    }
    float4 y0, y1;
    y0.x = fmaxf(acc0.x, 0.f); y0.y = fmaxf(acc0.y, 0.f);
    y0.z = fmaxf(acc0.z, 0.f); y0.w = fmaxf(acc0.w, 0.f);
    y1.x = fmaxf(acc1.x, 0.f); y1.y = fmaxf(acc1.y, 0.f);
    y1.z = fmaxf(acc1.z, 0.f); y1.w = fmaxf(acc1.w, 0.f);

    if (!FUSE) {
        if (n0g < N) *(float4*)&Yout[(size_t)n0g * HID + c0t] = y0;
        if (n1g < N) *(float4*)&Yout[(size_t)n1g * HID + c0t] = y1;
    } else {
        // ---- in-block pm for NEXT layer: PM/Th = fp16(y@W_top + b) ----
        __syncthreads();                       // all aggs reads done
        *(float4*)&aggs[r0 * AGP + c0t] = y0;  // stage y in aggs
        *(float4*)&aggs[r1 * AGP + c0t] = y1;
        __syncthreads();

        const int c2  = (tid & 31) * 4;        // 0..124 (128 out cols)
        const int nn0 = (tid >> 5) * 4;        // 4 nodes/thread
        const bool isM = (c2 < 64);
        const float* Wn = isM ? MwN : UwN;
        const float* bn = isM ? MbN : UbN;
        const int cc = isM ? c2 : c2 - 64;
        const float4 bv = *(const float4*)&bn[cc];
        float4 p0 = bv, p1 = bv, p2 = bv, p3 = bv;
        #pragma unroll 4
        for (int k = 0; k < 64; k += 4) {
            const float4 w0 = *(const float4*)&Wn[(k + 0) * 64 + cc];
            const float4 w1 = *(const float4*)&Wn[(k + 1) * 64 + cc];
            const float4 w2 = *(const float4*)&Wn[(k + 2) * 64 + cc];
            const float4 w3 = *(const float4*)&Wn[(k + 3) * 64 + cc];
            const float4 x0 = *(const float4*)&aggs[(nn0 + 0) * AGP + k];
            const float4 x1 = *(const float4*)&aggs[(nn0 + 1) * AGP + k];
            const float4 x2 = *(const float4*)&aggs[(nn0 + 2) * AGP + k];
            const float4 x3 = *(const float4*)&aggs[(nn0 + 3) * AGP + k];
            p0.x += x0.x * w0.x + x0.y * w1.x + x0.z * w2.x + x0.w * w3.x;
            p0.y += x0.x * w0.y + x0.y * w1.y + x0.z * w2.y + x0.w * w3.y;
            p0.z += x0.x * w0.z + x0.y * w1.z + x0.z * w2.z + x0.w * w3.z;
            p0.w += x0.x * w0.w + x0.y * w1.w + x0.z * w2.w + x0.w * w3.w;
            p1.x += x1.x * w0.x + x1.y * w1.x + x1.z * w2.x + x1.w * w3.x;
            p1.y += x1.x * w0.y + x1.y * w1.y + x1.z * w2.y + x1.w * w3.y;
            p1.z += x1.x * w0.z + x1.y * w1.z + x1.z * w2.z + x1.w * w3.z;
            p1.w += x1.x * w0.w + x1.y * w1.w + x1.z * w2.w + x1.w * w3.w;
            p2.x += x2.x * w0.x + x2.y * w1.x + x2.z * w2.x + x2.w * w3.x;
            p2.y += x2.x * w0.y + x2.y * w1.y + x2.z * w2.y + x2.w * w3.y;
            p2.z += x2.x * w0.z + x2.y * w1.z + x2.z * w2.z + x2.w * w3.z;
            p2.w += x2.x * w0.w + x2.y * w1.w + x2.z * w2.w + x2.w * w3.w;
            p3.x += x3.x * w0.x + x3.y * w1.x + x3.z * w2.x + x3.w * w3.x;
            p3.y += x3.x * w0.y + x3.y * w1.y + x3.z * w2.y + x3.w * w3.y;
            p3.z += x3.x * w0.z + x3.y * w1.z + x3.z * w2.z + x3.w * w3.z;
            p3.w += x3.x * w0.w + x3.y * w1.w + x3.z * w2.w + x3.w * w3.w;
        }
        float4 pr[4] = {p0, p1, p2, p3};
        #pragma unroll
        for (int ni = 0; ni < 4; ni++) {
            const int n = nbase + nn0 + ni;
            if (n < N) {
                H4 o;
                o.a = __float22half2_rn(make_float2(pr[ni].x, pr[ni].y));
                o.b = __float22half2_rn(make_float2(pr[ni].z, pr[ni].w));
                if (isM) *(H4*)&PMo[(size_t)n * 64 + cc] = o;
                else     *(H4*)&Tho[(size_t)n * 64 + cc] = o;
            }
        }
    }
}

// ===========================================================================
// pool_head: out[g] = (sum_{n in graph g} y[n]) . Ww + Wb  (sorted batch_idx)
// ===========================================================================
__global__ __launch_bounds__(256) void pool_head(
    const float* __restrict__ Y, const int* __restrict__ bidx,
    const float* __restrict__ Ww, const float* __restrict__ Wb,
    float* __restrict__ out, int N)
{
    const int g = blockIdx.x;
    int a = 0, b = N;
    while (a < b) { int m = (a + b) >> 1; if (bidx[m] < g) a = m + 1; else b = m; }
    const int lo = a;
    b = N;
    while (a < b) { int m = (a + b) >> 1; if (bidx[m] < g + 1) a = m + 1; else b = m; }
    const int hi = a;

    const int tid = threadIdx.x;
    const int c4 = tid & 15, nl = tid >> 4;
    float4 s = make_float4(0.f, 0.f, 0.f, 0.f);
    for (int n = lo + nl; n < hi; n += 16) {
        const float4 v = *(const float4*)&Y[(size_t)n * HID + c4 * 4];
        s.x += v.x; s.y += v.y; s.z += v.z; s.w += v.w;
    }
    __shared__ float red[16 * 68];
    *(float4*)&red[nl * 68 + c4 * 4] = s;
    __syncthreads();
    if (tid < 64) {
        float t = 0.f;
        #pragma unroll
        for (int r = 0; r < 16; r++) t += red[r * 68 + tid];
        t *= Ww[tid];
        #pragma unroll
        for (int off = 32; off; off >>= 1) t += __shfl_down(t, off);
        if (tid == 0) out[g] = t + Wb[0];
    }
}

extern "C" void kernel_launch(void* const* d_in, const int* in_sizes, int n_in,
                              void* d_out, int out_size, void* d_ws, size_t ws_size,
                              hipStream_t stream) {
    const float* H    = (const float*)d_in[0];
    const float* Xe   = (const float*)d_in[1];
    const int*   ids  = (const int*)d_in[2];
    const int*   bidx = (const int*)d_in[3];
    const float* Mw0  = (const float*)d_in[4];
    const float* Mb0  = (const float*)d_in[5];
    const float* Uw0  = (const float*)d_in[6];
    const float* Ub0  = (const float*)d_in[7];
    const float* MwH  = (const float*)d_in[8];   // [3, 80, 64]
    const float* MbH  = (const float*)d_in[9];
    const float* UwH  = (const float*)d_in[10];  // [3, 128, 64]
    const float* UbH  = (const float*)d_in[11];
    const float* Ww   = (const float*)d_in[12];
    const float* Wb   = (const float*)d_in[13];
    float* out = (float*)d_out;

    const int N = in_sizes[0] / 32;
    const int E = in_sizes[1] / 16;
    const int* src = ids;
    const int* dst = ids + E;

    // ---- workspace (same total footprint as baseline):
    // bufA: PMa,Tha (N*256B) | bufB: PMb,Thb (N*256B, old hbuf space) |
    // Xes E*32B | pks E*4B | rowptr | deg | bsums.
    // Final-layer f32 y overwrites bufA (yfin aliases PMa/Tha).
    __half* PMa  = (__half*)d_ws;                       // N*64 h
    __half* Tha  = PMa + (size_t)N * HID;               // N*64 h
    __half* PMb  = Tha + (size_t)N * HID;               // N*64 h
    __half* Thb  = PMb + (size_t)N * HID;               // N*64 h
    float*  yfin = (float*)d_ws;                        // N*64 f32 (= PMa+Tha)
    __half* Xes  = Thb + (size_t)N * HID;               // E*16 h
    unsigned* pks = (unsigned*)(Xes + (size_t)E * 16);  // E u32
    int* rowptr  = (int*)(pks + E);                     // N+1
    int* deg     = rowptr + (N + 1);                    // N
    int* bsums   = deg + N;                             // <=4096

    const int NB = (N + 2047) / 2048;
    const int eblocks = (E + 255) / 256;
    const int ntile   = (N + 31) / 32;

    // ---- CSR build + fp16 edge reorder ----
    hipMemsetAsync(deg, 0, (size_t)N * sizeof(int), stream);
    deg_count<<<eblocks, 256, 0, stream>>>(dst, deg, E);
    scan1<<<NB, 256, 0, stream>>>(deg, rowptr, bsums, N);
    scan2<<<1, 64, 0, stream>>>(bsums, NB);
    scan3<<<(N + 255) / 256, 256, 0, stream>>>(rowptr, bsums, N, E);
    hipMemsetAsync(deg, 0, (size_t)N * sizeof(int), stream);
    permute_k<<<eblocks, 256, 0, stream>>>(src, dst, rowptr, deg,
                                           Xe, Xes, pks, E);

    const float* MwH0 = MwH;                 const float* UwH0 = UwH;
    const float* MwH1 = MwH + 80 * HID;      const float* UwH1 = UwH + 128 * HID;
    const float* MwH2 = MwH + 2 * 80 * HID;  const float* UwH2 = UwH + 2 * 128 * HID;

    // ---- layer 0 (K1=32): pm from H, edge+fused-pm(next=H1 tops) ----
    pm_dual<32><<<ntile, 256, 0, stream>>>(H, Mw0, Mb0, Uw0, Ub0, PMa, Tha, N);
    edge_fused<true><<<ntile, 256, 0, stream>>>(
        PMa, Tha, Xes, pks, rowptr,
        Mw0 + 32 * HID, Uw0 + 32 * HID,
        MwH0, MbH, UwH0, UbH,
        PMb, Thb, nullptr, N);

    // ---- hidden layer 1: read B, fuse pm(next=H2 tops) -> A ----
    edge_fused<true><<<ntile, 256, 0, stream>>>(
        PMb, Thb, Xes, pks, rowptr,
        MwH0 + 64 * HID, UwH0 + 64 * HID,
        MwH1, MbH + HID, UwH1, UbH + HID,
        PMa, Tha, nullptr, N);

    // ---- hidden layer 2: read A, fuse pm(next=H3 tops) -> B ----
    edge_fused<true><<<ntile, 256, 0, stream>>>(
        PMa, Tha, Xes, pks, rowptr,
        MwH1 + 64 * HID, UwH1 + 64 * HID,
        MwH2, MbH + 2 * HID, UwH2, UbH + 2 * HID,
        PMb, Thb, nullptr, N);

    // ---- hidden layer 3 (last): read B, write f32 y into bufA ----
    edge_fused<false><<<ntile, 256, 0, stream>>>(
        PMb, Thb, Xes, pks, rowptr,
        MwH2 + 64 * HID, UwH2 + 64 * HID,
        nullptr, nullptr, nullptr, nullptr,
        nullptr, nullptr, yfin, N);

    // ---- pooling + head ----
    pool_head<<<256, 256, 0, stream>>>(yfin, bidx, Ww, Wb, out, N);
}